// Round 12
// baseline (311.919 us; speedup 1.0000x reference)
//
#include <hip/hip_runtime.h>
#include <hip/hip_bf16.h>
#include <stdint.h>
#include <stddef.h>

#define D_MODEL 4096
#define RANK    64
#define KC      512                 // fp32 k-elements per chunk
#define NCH     (D_MODEL / KC)      // 8
#define M_BLK   16
#define GRP     2                   // row-groups per block (pipelined)

typedef __attribute__((ext_vector_type(4)))  float f32x4;
typedef __attribute__((ext_vector_type(8)))  short bf16x8;

__device__ inline short f2bf1(float f) {
    union { __hip_bfloat16 t; short s; } c;
    c.t = __float2bfloat16(f);
    return c.s;
}
__device__ inline uint32_t pkbf(float a, float b) {
    union { __hip_bfloat162 t; uint32_t u; } c;
    c.t = __float22bfloat162_rn(make_float2(a, b));
    return c.u;
}

// ---------------------------------------------------------------------------
// Dequant + pack both weights into 16x16x32 MFMA B-fragment order (R10 layout,
// bench-proven): apk[((kb*4+n)*64+l)*8+j]  = a[16n+(l&15)][kb*32+(l>>4)*8+j]
//                bpk[((cb*2+ks)*64+l)*8+j] = b[cb*16+(l&15)][ks*32+(l>>4)*8+j]
// ---------------------------------------------------------------------------
__global__ __launch_bounds__(256) void dequant_pack_kernel(
        const int* __restrict__ qa, const float* __restrict__ qas,
        const int* __restrict__ qb, const float* __restrict__ qbs,
        short* __restrict__ apk, short* __restrict__ bpk) {
    const int idx = blockIdx.x * 256 + threadIdx.x;   // 0..32767
    const int l = idx & 63, t = idx >> 6;             // t: 0..511
    {   // a-side: t -> (kb 0..127, n 0..3)
        const int n = t & 3, kb = t >> 2;
        const int r = 16 * n + (l & 15);
        const int kbase = kb * 32 + ((l >> 4) << 3);
        const int* q = qa + (size_t)r * D_MODEL + kbase;
        const float s = qas[r * (D_MODEL / 32) + kb];
        bf16x8 o;
        #pragma unroll
        for (int j = 0; j < 8; ++j) o[j] = f2bf1((float)q[j] * s);
        *(bf16x8*)(apk + (size_t)idx * 8) = o;
    }
    {   // b-side: t -> (cb 0..255, ks 0..1)
        const int ks = t & 1, cb = t >> 1;
        const int d = cb * 16 + (l & 15);
        const int rbase = ks * 32 + ((l >> 4) << 3);
        const int* q = qb + (size_t)d * RANK + rbase;
        const float s = qbs[d * 2 + ks];
        bf16x8 o;
        #pragma unroll
        for (int j = 0; j < 8; ++j) o[j] = f2bf1((float)q[j] * s);
        *(bf16x8*)(bpk + (size_t)idx * 8) = o;
    }
}

// ---------------------------------------------------------------------------
// Fused kernel with intra-block group pipelining. Block = 512 thr (8 waves),
// processes GRP=2 consecutive 16-row groups; grid T/(16*2) = 512 -> 2
// blocks/CU (LDS 37376 B). Per group: double-buffered XOR-swizzled LDS
// stage of x, 8-wave split-K 16x16x32 MFMA (one barrier/chunk), cross-wave
// reduce -> h in LDS, phase 3 (h @ b^T) with NON-TEMPORAL stores.
// Pipelining: next group's chunk-0 loads issue right after this group's
// K-loop; chunk-0 ds_write + chunk-1 loads issue before phase 3, so this
// group's store burst + phase-3 compute overlap next group's HBM reads.
// ---------------------------------------------------------------------------
__global__ __launch_bounds__(512, 4) void fused_kernel(
        const float* __restrict__ x, const short* __restrict__ apk,
        const short* __restrict__ bpk, float* __restrict__ out) {
    // stage dbuf 2 x (16 rows x 512 bf16) = 32768 B, overlaid by
    // red[8][16][68] f32 = 34816 B; h_lds [16][80] bf16 = 2560 B after.
    __shared__ __align__(16) char smem[34816 + 2560];
    float* red   = (float*)smem;
    short* h_lds = (short*)(smem + 34816);

    const int tid  = threadIdx.x;
    const int lane = tid & 63;
    const int wave = tid >> 6;
    const int row16 = lane & 15;
    const int r4    = (lane >> 4) << 2;

    const int srow = tid >> 7;               // 0..3
    const int scol = (tid & 127) << 2;       // f32 col 0..508

    f32x4 xr[4];

    #define LOADX(xb_, c_)                                                     \
        _Pragma("unroll")                                                      \
        for (int r = 0; r < 4; ++r)                                            \
            xr[r] = *(const f32x4*)((xb_) + (size_t)(r * 4 + srow) * D_MODEL   \
                                    + (size_t)(c_) * KC + scol);
    #define WRITEX(bufofs_)                                                    \
        _Pragma("unroll")                                                      \
        for (int r = 0; r < 4; ++r) {                                          \
            const int row = r * 4 + srow;                                      \
            int byte = (bufofs_) + row * 1024 + (scol << 1);                   \
            byte ^= (row & 7) << 4;                                            \
            union { uint32_t w[2]; uint2 u; } p;                               \
            p.w[0] = pkbf(xr[r][0], xr[r][1]);                                 \
            p.w[1] = pkbf(xr[r][2], xr[r][3]);                                 \
            *(uint2*)(smem + byte) = p.u;                                      \
        }

    const int rb0 = blockIdx.x * (M_BLK * GRP);

    // ---- initial prologue for group 0 ----
    {
        const float* xb = x + (size_t)rb0 * D_MODEL;
        LOADX(xb, 0)
        WRITEX(0)
        LOADX(xb, 1)
    }
    __syncthreads();

    for (int g = 0; g < GRP; ++g) {
        const int rb = rb0 + g * M_BLK;
        const float* xb  = x + (size_t)rb * D_MODEL;
        const float* xbn = xb + (size_t)M_BLK * D_MODEL;   // next group

        f32x4 acc[4];
        #pragma unroll
        for (int n = 0; n < 4; ++n) acc[n] = (f32x4){0.f, 0.f, 0.f, 0.f};

        // ---- K loop: one barrier per chunk; wave w owns k [w*64, +64) ----
        for (int c = 0; c < NCH; ++c) {
            const char* sb = smem + (c & 1) * 16384;
            #pragma unroll
            for (int ks = 0; ks < 2; ++ks) {
                const int kin = wave * 64 + ks * 32 + ((lane >> 4) << 3);
                int byte = row16 * 1024 + (kin << 1);
                byte ^= (row16 & 7) << 4;
                bf16x8 af = *(const bf16x8*)(sb + byte);
                const int kbg = c * 16 + wave * 2 + ks;     // 32-wide k block
                #pragma unroll
                for (int n = 0; n < 4; ++n) {
                    bf16x8 bf = *(const bf16x8*)(apk +
                        ((size_t)((kbg * 4 + n) * 64 + lane) << 3));
                    acc[n] = __builtin_amdgcn_mfma_f32_16x16x32_bf16(
                        af, bf, acc[n], 0, 0, 0);
                }
            }
            if (c < NCH - 1) {
                WRITEX(((c + 1) & 1) * 16384)
                if (c < NCH - 2) LOADX(xb, c + 2)
            }
            __syncthreads();
        }

        // ---- issue next group's chunk-0 loads (overlap with phase 2/3) ----
        if (g + 1 < GRP) LOADX(xbn, 0)

        // ---- phase 2: cross-wave reduction (red overlays stage) ----
        #pragma unroll
        for (int n = 0; n < 4; ++n)
            #pragma unroll
            for (int j = 0; j < 4; ++j)
                red[(wave * 16 + r4 + j) * 68 + n * 16 + row16] = acc[n][j];
        __syncthreads();
        for (int e = tid; e < 16 * 64; e += 512) {
            const int r = e >> 6, cc = e & 63;
            float s = 0.f;
            #pragma unroll
            for (int w = 0; w < 8; ++w) s += red[(w * 16 + r) * 68 + cc];
            h_lds[r * 80 + cc] = f2bf1(s);
        }
        __syncthreads();

        // ---- stage next group's chunk 0 + issue chunk-1 loads ----
        if (g + 1 < GRP) {
            WRITEX(0)
            LOADX(xbn, 1)
        }

        // ---- phase 3: out[16][4096] = h @ b^T; wave w -> cols [w*512,+512) ----
        bf16x8 hf[2];
        #pragma unroll
        for (int ks = 0; ks < 2; ++ks)
            hf[ks] = *(const bf16x8*)(h_lds + row16 * 80 + ks * 32 + ((lane >> 4) << 3));

        #pragma unroll 4
        for (int n = 0; n < 32; ++n) {
            const int cb = wave * 32 + n;              // 16-col tile 0..255
            f32x4 a2 = (f32x4){0.f, 0.f, 0.f, 0.f};
            #pragma unroll
            for (int ks = 0; ks < 2; ++ks) {
                bf16x8 bf = *(const bf16x8*)(bpk +
                    ((size_t)(cb * 2 + ks) * 64 + lane) * 8);
                a2 = __builtin_amdgcn_mfma_f32_16x16x32_bf16(hf[ks], bf, a2, 0, 0, 0);
            }
            const int col = cb * 16 + row16;
            #pragma unroll
            for (int j = 0; j < 4; ++j)
                __builtin_nontemporal_store(a2[j],
                    &out[(size_t)(rb + r4 + j) * D_MODEL + col]);
        }

        if (g + 1 < GRP) __syncthreads();   // chunk-0 stage visible to all
    }

    #undef LOADX
    #undef WRITEX
}

// ---------------------------------------------------------------------------
extern "C" void kernel_launch(void* const* d_in, const int* in_sizes, int n_in,
                              void* d_out, int out_size, void* d_ws, size_t ws_size,
                              hipStream_t stream) {
    (void)n_in; (void)out_size; (void)ws_size;
    const float* x   = (const float*)d_in[0];
    const int*   qa  = (const int*)d_in[1];
    const float* qas = (const float*)d_in[2];
    const int*   qb  = (const int*)d_in[3];
    const float* qbs = (const float*)d_in[4];
    float* out = (float*)d_out;

    const int T = in_sizes[0] / D_MODEL;   // 16384

    short* apk = (short*)d_ws;                       // 64*4096 bf16 packed
    short* bpk = apk + (size_t)RANK * D_MODEL;       // 4096*64 bf16 packed

    dequant_pack_kernel<<<128, 256, 0, stream>>>(qa, qas, qb, qbs, apk, bpk);
    fused_kernel<<<T / (M_BLK * GRP), 512, 0, stream>>>(x, apk, bpk, out);
}

// Round 13
// 186.513 us; speedup vs baseline: 1.6724x; 1.6724x over previous
//
#include <hip/hip_runtime.h>
#include <hip/hip_bf16.h>
#include <stdint.h>
#include <stddef.h>

#define D_MODEL 4096
#define RANK    64
#define KC      512                 // fp32 k-elements per chunk
#define NCH     (D_MODEL / KC)      // 8
#define M_BLK   32

typedef __attribute__((ext_vector_type(4)))  float f32x4;
typedef __attribute__((ext_vector_type(16))) float f32x16;
typedef __attribute__((ext_vector_type(8)))  short bf16x8;

__device__ inline short f2bf1(float f) {
    union { __hip_bfloat16 t; short s; } c;
    c.t = __float2bfloat16(f);
    return c.s;
}
__device__ inline uint32_t pkbf(float a, float b) {
    union { __hip_bfloat162 t; uint32_t u; } c;
    c.t = __float22bfloat162_rn(make_float2(a, b));
    return c.u;
}

// ---------------------------------------------------------------------------
// Dequant + pack both weights into MFMA-fragment order (R11 layouts).
// apk (16x16x32 B-frag): apk[((kb*4+n)*64+l)*8+j] = a[16n+(l&15)][kb*32+(l>>4)*8+j]
// bpk (32x32x16 B-frag): bpk[((cb*4+ks)*64+l)*8+j] = b[cb*32+(l&31)][ks*16+(l>>5)*8+j]
// ---------------------------------------------------------------------------
__global__ __launch_bounds__(256) void dequant_pack_kernel(
        const int* __restrict__ qa, const float* __restrict__ qas,
        const int* __restrict__ qb, const float* __restrict__ qbs,
        short* __restrict__ apk, short* __restrict__ bpk) {
    const int idx = blockIdx.x * 256 + threadIdx.x;   // 0..32767
    const int l = idx & 63, t = idx >> 6;             // t: 0..511
    {   // a-side: t -> (kb 0..127, n 0..3)
        const int n = t & 3, kb = t >> 2;
        const int r = 16 * n + (l & 15);
        const int kbase = kb * 32 + ((l >> 4) << 3);
        const int* q = qa + (size_t)r * D_MODEL + kbase;
        const float s = qas[r * (D_MODEL / 32) + kb];
        bf16x8 o;
        #pragma unroll
        for (int j = 0; j < 8; ++j) o[j] = f2bf1((float)q[j] * s);
        *(bf16x8*)(apk + (size_t)idx * 8) = o;
    }
    {   // b-side: t -> (cb 0..127, ks 0..3)
        const int ks = t & 3, cb = t >> 2;
        const int d = cb * 32 + (l & 31);
        const int rbase = ks * 16 + ((l >> 5) << 3);
        const int* q = qb + (size_t)d * RANK + rbase;
        const float s = qbs[d * 2 + (ks >> 1)];
        bf16x8 o;
        #pragma unroll
        for (int j = 0; j < 8; ++j) o[j] = f2bf1((float)q[j] * s);
        *(bf16x8*)(bpk + (size_t)idx * 8) = o;
    }
}

// ---------------------------------------------------------------------------
// Fused kernel = R11 (proven 124 us) + 3-deep dual-register-set x prefetch.
// Block = 32 rows, 512 thr (8 waves), grid T/32 = 512, 2 blocks/CU.
// K-loop fully unrolled; xrA holds odd chunks, xrB even chunks, so WRITEX of
// chunk c+1 waits only on its own set's 8 loads (effective vmcnt(8)) while
// the other set's 8 loads stay in flight -> per-chunk drain stall halved.
// Phase 3 nt stores keep the 128B-contiguous pattern (R12 lesson: nt with
// 64B segments causes ~2.2x write amplification + RMW fetches).
// ---------------------------------------------------------------------------
__global__ __launch_bounds__(512, 4) void fused_kernel(
        const float* __restrict__ x, const short* __restrict__ apk,
        const short* __restrict__ bpk, float* __restrict__ out) {
    // smem: stage dbuf 2 x (32 x 512 bf16) = 65536 B, overlaid by
    // red[4][32][68] f32 (34816 B) in phase 2; h_lds 32x80 bf16 after.
    __shared__ __align__(16) char smem[65536 + 5120];
    float* red   = (float*)smem;
    short* h_lds = (short*)(smem + 65536);

    const int tid  = threadIdx.x;
    const int lane = tid & 63;
    const int wave = tid >> 6;
    const int rb   = blockIdx.x * M_BLK;

    const int srow = tid >> 7;               // 0..3
    const int scol = (tid & 127) << 2;       // float col 0,4,...,508
    const float* xbase = x + (size_t)rb * D_MODEL;

    f32x4 xrA[8], xrB[8];

    #define LOADX(dst_, c_)                                                    \
        _Pragma("unroll")                                                      \
        for (int r = 0; r < 8; ++r)                                            \
            dst_[r] = *(const f32x4*)(xbase + (size_t)(r * 4 + srow) * D_MODEL \
                                      + (size_t)(c_) * KC + scol);
    #define WRITEX(src_, bufofs_)                                              \
        _Pragma("unroll")                                                      \
        for (int r = 0; r < 8; ++r) {                                          \
            const int row = r * 4 + srow;                                      \
            int byte = (bufofs_) + row * 1024 + (scol << 1);                   \
            byte ^= (row & 7) << 4;                                            \
            union { uint32_t w[2]; uint2 u; } p;                               \
            p.w[0] = pkbf(src_[r][0], src_[r][1]);                             \
            p.w[1] = pkbf(src_[r][2], src_[r][3]);                             \
            *(uint2*)(smem + byte) = p.u;                                      \
        }

    // ---- prologue: stage chunk 0; launch loads for chunks 1 (A) and 2 (B) ----
    LOADX(xrA, 0)
    WRITEX(xrA, 0)
    LOADX(xrA, 1)
    LOADX(xrB, 2)
    __syncthreads();

    f32x4 acc[2][4];
    #pragma unroll
    for (int m = 0; m < 2; ++m)
        #pragma unroll
        for (int n = 0; n < 4; ++n)
            acc[m][n] = (f32x4){0.f, 0.f, 0.f, 0.f};

    // ---- main K loop (fully unrolled; one barrier per chunk) ----
    #pragma unroll
    for (int c = 0; c < NCH; ++c) {
        const char* sb = smem + (c & 1) * 32768;
        #pragma unroll
        for (int ks = 0; ks < 2; ++ks) {
            const int kin = wave * 64 + ks * 32 + ((lane >> 4) << 3);
            bf16x8 af[2];
            #pragma unroll
            for (int m = 0; m < 2; ++m) {
                const int row = m * 16 + (lane & 15);
                int byte = row * 1024 + (kin << 1);
                byte ^= (row & 7) << 4;
                af[m] = *(const bf16x8*)(sb + byte);
            }
            const int kbg = c * 16 + wave * 2 + ks;      // global 32-k block
            #pragma unroll
            for (int n = 0; n < 4; ++n) {
                bf16x8 bf = *(const bf16x8*)(apk + ((size_t)((kbg * 4 + n) * 64 + lane) << 3));
                #pragma unroll
                for (int m = 0; m < 2; ++m)
                    acc[m][n] = __builtin_amdgcn_mfma_f32_16x16x32_bf16(
                        af[m], bf, acc[m][n], 0, 0, 0);
            }
        }
        if (c < NCH - 1) {
            // chunk c+1's data: odd chunks live in A, even in B (static parity)
            if ((c + 1) & 1) {
                WRITEX(xrA, ((c + 1) & 1) * 32768)
                if (c + 3 < NCH) LOADX(xrA, c + 3)
            } else {
                WRITEX(xrB, ((c + 1) & 1) * 32768)
                if (c + 3 < NCH) LOADX(xrB, c + 3)
            }
        }
        __syncthreads();
    }

    // ---- phase 2: cross-wave reduction (red overlays stage) ----
    const int r4 = (lane >> 4) << 2;
    if (wave < 4) {
        #pragma unroll
        for (int m = 0; m < 2; ++m)
            #pragma unroll
            for (int n = 0; n < 4; ++n)
                #pragma unroll
                for (int j = 0; j < 4; ++j)
                    red[(wave * 32 + m * 16 + r4 + j) * 68 + n * 16 + (lane & 15)] =
                        acc[m][n][j];
    }
    __syncthreads();
    if (wave >= 4) {
        #pragma unroll
        for (int m = 0; m < 2; ++m)
            #pragma unroll
            for (int n = 0; n < 4; ++n)
                #pragma unroll
                for (int j = 0; j < 4; ++j)
                    red[((wave - 4) * 32 + m * 16 + r4 + j) * 68 + n * 16 + (lane & 15)] +=
                        acc[m][n][j];
    }
    __syncthreads();
    for (int e = tid; e < 32 * 64; e += 512) {
        const int r = e >> 6, cc = e & 63;
        float s = red[(0 * 32 + r) * 68 + cc] + red[(1 * 32 + r) * 68 + cc]
                + red[(2 * 32 + r) * 68 + cc] + red[(3 * 32 + r) * 68 + cc];
        h_lds[r * 80 + cc] = f2bf1(s);
    }
    __syncthreads();

    // ---- phase 3: out[32][4096] = h @ b^T; wave w -> cols [w*512, +512) ----
    bf16x8 hf[4];
    #pragma unroll
    for (int ks = 0; ks < 4; ++ks)
        hf[ks] = *(const bf16x8*)(h_lds + (lane & 31) * 80 + ks * 16 + ((lane >> 5) << 3));

    #pragma unroll
    for (int n = 0; n < 16; ++n) {
        const int cb32 = wave * 16 + n;
        const int col  = cb32 * 32 + (lane & 31);
        f32x16 a2;
        #pragma unroll
        for (int j = 0; j < 16; ++j) a2[j] = 0.f;
        #pragma unroll
        for (int ks = 0; ks < 4; ++ks) {
            bf16x8 bf = *(const bf16x8*)(bpk + ((size_t)((cb32 * 4 + ks) * 64 + lane) << 3));
            a2 = __builtin_amdgcn_mfma_f32_32x32x16_bf16(hf[ks], bf, a2, 0, 0, 0);
        }
        #pragma unroll
        for (int reg = 0; reg < 16; ++reg) {
            const int r = (reg & 3) + 8 * (reg >> 2) + ((lane >> 5) << 2);
            __builtin_nontemporal_store(a2[reg],
                &out[(size_t)(rb + r) * D_MODEL + col]);
        }
    }

    #undef LOADX
    #undef WRITEX
}

// ---------------------------------------------------------------------------
extern "C" void kernel_launch(void* const* d_in, const int* in_sizes, int n_in,
                              void* d_out, int out_size, void* d_ws, size_t ws_size,
                              hipStream_t stream) {
    (void)n_in; (void)out_size; (void)ws_size;
    const float* x   = (const float*)d_in[0];
    const int*   qa  = (const int*)d_in[1];
    const float* qas = (const float*)d_in[2];
    const int*   qb  = (const int*)d_in[3];
    const float* qbs = (const float*)d_in[4];
    float* out = (float*)d_out;

    const int T = in_sizes[0] / D_MODEL;   // 16384

    short* apk = (short*)d_ws;                       // 64*4096 bf16 packed
    short* bpk = apk + (size_t)RANK * D_MODEL;       // 4096*64 bf16 packed

    dequant_pack_kernel<<<128, 256, 0, stream>>>(qa, qas, qb, qbs, apk, bpk);
    fused_kernel<<<T / M_BLK, 512, 0, stream>>>(x, apk, bpk, out);
}

// Round 14
// 148.302 us; speedup vs baseline: 2.1033x; 1.2577x over previous
//
#include <hip/hip_runtime.h>
#include <hip/hip_bf16.h>
#include <stdint.h>
#include <stddef.h>

#define D_MODEL 4096
#define RANK    64
#define KC      512                 // fp32 k-elements per chunk
#define NCH     (D_MODEL / KC)      // 8
#define M_BLK   32
#define GRP     2                   // groups per block (write of g0 overlaps read of g1)

typedef __attribute__((ext_vector_type(4)))  float f32x4;
typedef __attribute__((ext_vector_type(16))) float f32x16;
typedef __attribute__((ext_vector_type(8)))  short bf16x8;

__device__ inline short f2bf1(float f) {
    union { __hip_bfloat16 t; short s; } c;
    c.t = __float2bfloat16(f);
    return c.s;
}
__device__ inline uint32_t pkbf(float a, float b) {
    union { __hip_bfloat162 t; uint32_t u; } c;
    c.t = __float22bfloat162_rn(make_float2(a, b));
    return c.u;
}

// ---------------------------------------------------------------------------
// Dequant + pack both weights into MFMA-fragment order (R11 layouts).
// apk (16x16x32 B-frag): apk[((kb*4+n)*64+l)*8+j] = a[16n+(l&15)][kb*32+(l>>4)*8+j]
// bpk (32x32x16 B-frag): bpk[((cb*4+ks)*64+l)*8+j] = b[cb*32+(l&31)][ks*16+(l>>5)*8+j]
// ---------------------------------------------------------------------------
__global__ __launch_bounds__(256) void dequant_pack_kernel(
        const int* __restrict__ qa, const float* __restrict__ qas,
        const int* __restrict__ qb, const float* __restrict__ qbs,
        short* __restrict__ apk, short* __restrict__ bpk) {
    const int idx = blockIdx.x * 256 + threadIdx.x;   // 0..32767
    const int l = idx & 63, t = idx >> 6;             // t: 0..511
    {   // a-side: t -> (kb 0..127, n 0..3)
        const int n = t & 3, kb = t >> 2;
        const int r = 16 * n + (l & 15);
        const int kbase = kb * 32 + ((l >> 4) << 3);
        const int* q = qa + (size_t)r * D_MODEL + kbase;
        const float s = qas[r * (D_MODEL / 32) + kb];
        bf16x8 o;
        #pragma unroll
        for (int j = 0; j < 8; ++j) o[j] = f2bf1((float)q[j] * s);
        *(bf16x8*)(apk + (size_t)idx * 8) = o;
    }
    {   // b-side: t -> (cb 0..127, ks 0..3)
        const int ks = t & 3, cb = t >> 2;
        const int d = cb * 32 + (l & 31);
        const int rbase = ks * 16 + ((l >> 5) << 3);
        const int* q = qb + (size_t)d * RANK + rbase;
        const float s = qbs[d * 2 + (ks >> 1)];
        bf16x8 o;
        #pragma unroll
        for (int j = 0; j < 8; ++j) o[j] = f2bf1((float)q[j] * s);
        *(bf16x8*)(bpk + (size_t)idx * 8) = o;
    }
}

// ---------------------------------------------------------------------------
// Fused kernel: R11 structure + GRP=2 group pipelining with distributed
// stores. Block = 512 thr (8 waves), 64 rows (2 groups of 32), grid 256
// (1 block/CU). Per group: dbuf XOR-swizzled LDS stage, split-K-8 16x16x32
// MFMA, one barrier/chunk, dual-register-set 3-deep x prefetch (fits: 1
// block/CU -> VGPR cap 256 via launch_bounds(512,1); R5/R13 spills were
// register-cap artifacts). Group 0's phase-3 (32x32 MFMA + nt 128B-segment
// stores) is distributed 2-tiles/wave/chunk into group 1's K-loop, so g0's
// write burst drains under g1's read stream. Tail: g1's phase 3.
// ---------------------------------------------------------------------------
__global__ __launch_bounds__(512, 1) void fused_kernel(
        const float* __restrict__ x, const short* __restrict__ apk,
        const short* __restrict__ bpk, float* __restrict__ out) {
    // smem: stage dbuf 2 x (32 x 512 bf16) = 65536 B, overlaid by
    // red[4][32][68] f32 (34816 B) during reduces; h_lds 32x80 bf16 after.
    __shared__ __align__(16) char smem[65536 + 5120];
    float* red   = (float*)smem;
    short* h_lds = (short*)(smem + 65536);

    const int tid  = threadIdx.x;
    const int lane = tid & 63;
    const int wave = tid >> 6;
    const int rb0  = blockIdx.x * (M_BLK * GRP);

    const int srow = tid >> 7;               // 0..3
    const int scol = (tid & 127) << 2;       // float col 0,4,...,508
    const float* xb0 = x + (size_t)rb0 * D_MODEL;
    const float* xb1 = xb0 + (size_t)M_BLK * D_MODEL;

    f32x4 xrA[8], xrB[8];
    f32x4 acc[2][4];

    #define LOADX(dst_, base_, c_)                                             \
        _Pragma("unroll")                                                      \
        for (int r = 0; r < 8; ++r)                                            \
            dst_[r] = *(const f32x4*)((base_) + (size_t)(r * 4 + srow) * D_MODEL \
                                      + (size_t)(c_) * KC + scol);
    #define WRITEX(src_, bufofs_)                                              \
        _Pragma("unroll")                                                      \
        for (int r = 0; r < 8; ++r) {                                          \
            const int row = r * 4 + srow;                                      \
            int byte = (bufofs_) + row * 1024 + (scol << 1);                   \
            byte ^= (row & 7) << 4;                                            \
            union { uint32_t w[2]; uint2 u; } p;                               \
            p.w[0] = pkbf(src_[r][0], src_[r][1]);                             \
            p.w[1] = pkbf(src_[r][2], src_[r][3]);                             \
            *(uint2*)(smem + byte) = p.u;                                      \
        }
    // one chunk of the K-loop body (MFMA from staged buffer + apk)
    #define MFMA_CHUNK(c_)                                                     \
        {                                                                      \
            const char* sb = smem + ((c_) & 1) * 32768;                        \
            _Pragma("unroll")                                                  \
            for (int ks = 0; ks < 2; ++ks) {                                   \
                const int kin = wave * 64 + ks * 32 + ((lane >> 4) << 3);      \
                bf16x8 af[2];                                                  \
                _Pragma("unroll")                                              \
                for (int m = 0; m < 2; ++m) {                                  \
                    const int row = m * 16 + (lane & 15);                      \
                    int byte = row * 1024 + (kin << 1);                        \
                    byte ^= (row & 7) << 4;                                    \
                    af[m] = *(const bf16x8*)(sb + byte);                       \
                }                                                              \
                const int kbg = (c_) * 16 + wave * 2 + ks;                     \
                _Pragma("unroll")                                              \
                for (int n = 0; n < 4; ++n) {                                  \
                    bf16x8 bf = *(const bf16x8*)(apk +                         \
                        ((size_t)((kbg * 4 + n) * 64 + lane) << 3));           \
                    _Pragma("unroll")                                          \
                    for (int m = 0; m < 2; ++m)                                \
                        acc[m][n] = __builtin_amdgcn_mfma_f32_16x16x32_bf16(   \
                            af[m], bf, acc[m][n], 0, 0, 0);                    \
                }                                                              \
            }                                                                  \
        }
    // stage/prefetch step after chunk c's MFMA (dual-set parity)
    #define STAGE_STEP(base_, c_)                                              \
        if ((c_) < NCH - 1) {                                                  \
            if (((c_) + 1) & 1) {                                              \
                WRITEX(xrA, (((c_) + 1) & 1) * 32768)                          \
                if ((c_) + 3 < NCH) LOADX(xrA, base_, (c_) + 3)                \
            } else {                                                           \
                WRITEX(xrB, (((c_) + 1) & 1) * 32768)                          \
                if ((c_) + 3 < NCH) LOADX(xrB, base_, (c_) + 3)                \
            }                                                                  \
        }
    // phase-3 tile: 32x32 MFMA column-tile cb_ for rows rb_, nt 128B stores
    #define STORE_TILE(rb_, cb_, hf_)                                          \
        {                                                                      \
            f32x16 a2;                                                         \
            _Pragma("unroll")                                                  \
            for (int j = 0; j < 16; ++j) a2[j] = 0.f;                          \
            _Pragma("unroll")                                                  \
            for (int ks = 0; ks < 4; ++ks) {                                   \
                bf16x8 bf = *(const bf16x8*)(bpk +                             \
                    ((size_t)(((cb_) * 4 + ks) * 64 + lane) << 3));            \
                a2 = __builtin_amdgcn_mfma_f32_32x32x16_bf16(hf_[ks], bf, a2,  \
                                                             0, 0, 0);         \
            }                                                                  \
            const int col = (cb_) * 32 + (lane & 31);                          \
            _Pragma("unroll")                                                  \
            for (int reg = 0; reg < 16; ++reg) {                               \
                const int r = (reg & 3) + 8 * (reg >> 2) + ((lane >> 5) << 2); \
                __builtin_nontemporal_store(a2[reg],                           \
                    &out[(size_t)((rb_) + r) * D_MODEL + col]);                \
            }                                                                  \
        }
    #define ACC_INIT                                                           \
        _Pragma("unroll")                                                      \
        for (int m = 0; m < 2; ++m)                                            \
            _Pragma("unroll")                                                  \
            for (int n = 0; n < 4; ++n)                                        \
                acc[m][n] = (f32x4){0.f, 0.f, 0.f, 0.f};
    #define REDUCE_TO_H                                                        \
        {                                                                      \
            const int r4 = (lane >> 4) << 2;                                   \
            if (wave < 4) {                                                    \
                _Pragma("unroll")                                              \
                for (int m = 0; m < 2; ++m)                                    \
                    _Pragma("unroll")                                          \
                    for (int n = 0; n < 4; ++n)                                \
                        _Pragma("unroll")                                      \
                        for (int j = 0; j < 4; ++j)                            \
                            red[(wave * 32 + m * 16 + r4 + j) * 68 + n * 16 +  \
                                (lane & 15)] = acc[m][n][j];                   \
            }                                                                  \
            __syncthreads();                                                   \
            if (wave >= 4) {                                                   \
                _Pragma("unroll")                                              \
                for (int m = 0; m < 2; ++m)                                    \
                    _Pragma("unroll")                                          \
                    for (int n = 0; n < 4; ++n)                                \
                        _Pragma("unroll")                                      \
                        for (int j = 0; j < 4; ++j)                            \
                            red[((wave - 4) * 32 + m * 16 + r4 + j) * 68 +     \
                                n * 16 + (lane & 15)] += acc[m][n][j];         \
            }                                                                  \
            __syncthreads();                                                   \
            for (int e = tid; e < 32 * 64; e += 512) {                         \
                const int r = e >> 6, cc = e & 63;                             \
                float s = red[(0 * 32 + r) * 68 + cc]                          \
                        + red[(1 * 32 + r) * 68 + cc]                          \
                        + red[(2 * 32 + r) * 68 + cc]                          \
                        + red[(3 * 32 + r) * 68 + cc];                         \
                h_lds[r * 80 + cc] = f2bf1(s);                                 \
            }                                                                  \
            __syncthreads();                                                   \
        }
    #define LOAD_HF(hf_)                                                       \
        _Pragma("unroll")                                                      \
        for (int ks = 0; ks < 4; ++ks)                                         \
            hf_[ks] = *(const bf16x8*)(h_lds + (lane & 31) * 80 + ks * 16 +    \
                                       ((lane >> 5) << 3));

    // ================= group 0: read + reduce =================
    LOADX(xrA, xb0, 0)
    WRITEX(xrA, 0)
    LOADX(xrA, xb0, 1)
    LOADX(xrB, xb0, 2)
    __syncthreads();
    ACC_INIT
    #pragma unroll
    for (int c = 0; c < NCH; ++c) {
        MFMA_CHUNK(c)
        STAGE_STEP(xb0, c)
        __syncthreads();
    }

    // issue g1 chunk-0 loads before the reduce (overlaps it)
    LOADX(xrA, xb1, 0)
    REDUCE_TO_H                       // h0 -> h_lds

    bf16x8 hf0[4];
    LOAD_HF(hf0)

    // stage g1 chunk 0 (red reads done), launch chunks 1 & 2
    WRITEX(xrA, 0)
    LOADX(xrA, xb1, 1)
    LOADX(xrB, xb1, 2)
    __syncthreads();

    // ========== group 1 K-loop with g0's stores distributed ==========
    ACC_INIT
    #pragma unroll
    for (int c = 0; c < NCH; ++c) {
        MFMA_CHUNK(c)
        // 2 of group-0's 16 phase-3 tiles per wave per chunk
        STORE_TILE(rb0, wave * 16 + 2 * c,     hf0)
        STORE_TILE(rb0, wave * 16 + 2 * c + 1, hf0)
        STAGE_STEP(xb1, c)
        __syncthreads();
    }

    // ================= group 1 reduce + phase-3 tail =================
    REDUCE_TO_H                       // h1 -> h_lds
    bf16x8 hf1[4];
    LOAD_HF(hf1)
    #pragma unroll
    for (int n = 0; n < 16; ++n) {
        STORE_TILE(rb0 + M_BLK, wave * 16 + n, hf1)
    }

    #undef LOADX
    #undef WRITEX
    #undef MFMA_CHUNK
    #undef STAGE_STEP
    #undef STORE_TILE
    #undef ACC_INIT
    #undef REDUCE_TO_H
    #undef LOAD_HF
}

// ---------------------------------------------------------------------------
extern "C" void kernel_launch(void* const* d_in, const int* in_sizes, int n_in,
                              void* d_out, int out_size, void* d_ws, size_t ws_size,
                              hipStream_t stream) {
    (void)n_in; (void)out_size; (void)ws_size;
    const float* x   = (const float*)d_in[0];
    const int*   qa  = (const int*)d_in[1];
    const float* qas = (const float*)d_in[2];
    const int*   qb  = (const int*)d_in[3];
    const float* qbs = (const float*)d_in[4];
    float* out = (float*)d_out;

    const int T = in_sizes[0] / D_MODEL;   // 16384

    short* apk = (short*)d_ws;                       // 64*4096 bf16 packed
    short* bpk = apk + (size_t)RANK * D_MODEL;       // 4096*64 bf16 packed

    dequant_pack_kernel<<<128, 256, 0, stream>>>(qa, qas, qb, qbs, apk, bpk);
    fused_kernel<<<T / (M_BLK * GRP), 512, 0, stream>>>(x, apk, bpk, out);
}

// Round 15
// 121.516 us; speedup vs baseline: 2.5669x; 1.2204x over previous
//
#include <hip/hip_runtime.h>
#include <hip/hip_bf16.h>
#include <stdint.h>
#include <stddef.h>

#define D_MODEL 4096
#define RANK    64
#define KC      512                 // fp32 k-elements per chunk
#define NCH     (D_MODEL / KC)      // 8
#define M_BLK   32

typedef __attribute__((ext_vector_type(4)))  float f32x4;
typedef __attribute__((ext_vector_type(16))) float f32x16;
typedef __attribute__((ext_vector_type(8)))  short bf16x8;

__device__ inline short f2bf1(float f) {
    union { __hip_bfloat16 t; short s; } c;
    c.t = __float2bfloat16(f);
    return c.s;
}
__device__ inline uint32_t pkbf(float a, float b) {
    union { __hip_bfloat162 t; uint32_t u; } c;
    c.t = __float22bfloat162_rn(make_float2(a, b));
    return c.u;
}

// ---------------------------------------------------------------------------
// Dequant + pack both weights into MFMA-fragment order (R4/R11 layouts).
// apk (16x16x32 B-frag): apk[((kb*4+n)*64+l)*8+j] = a[16n+(l&15)][kb*32+(l>>4)*8+j]
// bpk (32x32x16 B-frag): bpk[((cb*4+ks)*64+l)*8+j] = b[cb*32+(l&31)][ks*16+(l>>5)*8+j]
// Regular stores: apk/bpk are re-read every call and want L2/L3 residency.
// ---------------------------------------------------------------------------
__global__ __launch_bounds__(256) void dequant_pack_kernel(
        const int* __restrict__ qa, const float* __restrict__ qas,
        const int* __restrict__ qb, const float* __restrict__ qbs,
        short* __restrict__ apk, short* __restrict__ bpk) {
    const int idx = blockIdx.x * 256 + threadIdx.x;   // 0..32767
    const int l = idx & 63, t = idx >> 6;             // t: 0..511
    {   // a-side: t -> (kb 0..127, n 0..3)
        const int n = t & 3, kb = t >> 2;
        const int r = 16 * n + (l & 15);
        const int kbase = kb * 32 + ((l >> 4) << 3);
        const int* q = qa + (size_t)r * D_MODEL + kbase;
        const float s = qas[r * (D_MODEL / 32) + kb];
        bf16x8 o;
        #pragma unroll
        for (int j = 0; j < 8; ++j) o[j] = f2bf1((float)q[j] * s);
        *(bf16x8*)(apk + (size_t)idx * 8) = o;
    }
    {   // b-side: t -> (cb 0..127, ks 0..3)
        const int ks = t & 3, cb = t >> 2;
        const int d = cb * 32 + (l & 31);
        const int rbase = ks * 16 + ((l >> 5) << 3);
        const int* q = qb + (size_t)d * RANK + rbase;
        const float s = qbs[d * 2 + (ks >> 1)];
        bf16x8 o;
        #pragma unroll
        for (int j = 0; j < 8; ++j) o[j] = f2bf1((float)q[j] * s);
        *(bf16x8*)(bpk + (size_t)idx * 8) = o;
    }
}

// ---------------------------------------------------------------------------
// Fused kernel (R11, best measured at 124.1 us): block = 32 rows, 512 thr
// (8 waves), grid T/32 = 512, 2 blocks/CU. Double-buffered XOR-swizzled LDS
// stage of x, 8-wave split-K 16x16x32 MFMA, one barrier per chunk, 2-chunk
// register prefetch (single 8-reg set; dual-set and deeper variants spill —
// R5/R13: visible as FETCH/WRITE growth).
// Phase 2: fp32 cross-wave reduce -> h bf16 in LDS (h never in HBM).
// Phase 3: out = h @ b^T, 32x32x16 MFMA, NON-TEMPORAL stores in 128B
// contiguous segments (R12: nt with 64B segments => 2.2x write
// amplification; R11's 32-col tiles are the proven pattern).
// ---------------------------------------------------------------------------
__global__ __launch_bounds__(512, 4) void fused_kernel(
        const float* __restrict__ x, const short* __restrict__ apk,
        const short* __restrict__ bpk, float* __restrict__ out) {
    // smem: stage double buffer 2 x (32 rows x 512 bf16) = 65536 B,
    //       overlaid by red[4][32][68] f32 (34816 B) in phase 2;
    //       h_lds 32x80 bf16 = 5120 B after the stage region.
    __shared__ __align__(16) char smem[65536 + 5120];
    float* red   = (float*)smem;
    short* h_lds = (short*)(smem + 65536);

    const int tid  = threadIdx.x;
    const int lane = tid & 63;
    const int wave = tid >> 6;
    const int rb   = blockIdx.x * M_BLK;

    const int srow = tid >> 7;               // 0..3
    const int scol = (tid & 127) << 2;       // float col 0,4,...,508
    const float* xb = x + (size_t)rb * D_MODEL;

    // ---- prologue: stage chunk 0, prefetch chunk 1 ----
    f32x4 xr[8];
    #pragma unroll
    for (int r = 0; r < 8; ++r)
        xr[r] = *(const f32x4*)(xb + (size_t)(r * 4 + srow) * D_MODEL + scol);
    #pragma unroll
    for (int r = 0; r < 8; ++r) {
        const int row = r * 4 + srow;
        int byte = row * 1024 + (scol << 1);
        byte ^= (row & 7) << 4;
        union { uint32_t w[2]; uint2 u; } p;
        p.w[0] = pkbf(xr[r][0], xr[r][1]);
        p.w[1] = pkbf(xr[r][2], xr[r][3]);
        *(uint2*)(smem + byte) = p.u;
    }
    #pragma unroll
    for (int r = 0; r < 8; ++r)
        xr[r] = *(const f32x4*)(xb + (size_t)(r * 4 + srow) * D_MODEL + KC + scol);
    __syncthreads();

    f32x4 acc[2][4];
    #pragma unroll
    for (int m = 0; m < 2; ++m)
        #pragma unroll
        for (int n = 0; n < 4; ++n)
            acc[m][n] = (f32x4){0.f, 0.f, 0.f, 0.f};

    // ---- main K loop: one barrier per chunk ----
    for (int c = 0; c < NCH; ++c) {
        const char* sb = smem + (c & 1) * 32768;
        #pragma unroll
        for (int ks = 0; ks < 2; ++ks) {
            const int kin = wave * 64 + ks * 32 + ((lane >> 4) << 3);
            bf16x8 af[2];
            #pragma unroll
            for (int m = 0; m < 2; ++m) {
                const int row = m * 16 + (lane & 15);
                int byte = row * 1024 + (kin << 1);
                byte ^= (row & 7) << 4;
                af[m] = *(const bf16x8*)(sb + byte);
            }
            const int kbg = c * 16 + wave * 2 + ks;      // global 32-k block
            #pragma unroll
            for (int n = 0; n < 4; ++n) {
                bf16x8 bf = *(const bf16x8*)(apk + ((size_t)((kbg * 4 + n) * 64 + lane) << 3));
                #pragma unroll
                for (int m = 0; m < 2; ++m)
                    acc[m][n] = __builtin_amdgcn_mfma_f32_16x16x32_bf16(
                        af[m], bf, acc[m][n], 0, 0, 0);
            }
        }
        if (c < NCH - 1) {
            char* sw = smem + ((c + 1) & 1) * 32768;
            #pragma unroll
            for (int r = 0; r < 8; ++r) {
                const int row = r * 4 + srow;
                int byte = row * 1024 + (scol << 1);
                byte ^= (row & 7) << 4;
                union { uint32_t w[2]; uint2 u; } p;
                p.w[0] = pkbf(xr[r][0], xr[r][1]);
                p.w[1] = pkbf(xr[r][2], xr[r][3]);
                *(uint2*)(sw + byte) = p.u;
            }
            if (c < NCH - 2) {
                #pragma unroll
                for (int r = 0; r < 8; ++r)
                    xr[r] = *(const f32x4*)(xb + (size_t)(r * 4 + srow) * D_MODEL
                                            + (size_t)(c + 2) * KC + scol);
            }
        }
        __syncthreads();
    }

    // ---- phase 2: cross-wave reduction (red overlays stage) ----
    const int r4 = (lane >> 4) << 2;
    if (wave < 4) {
        #pragma unroll
        for (int m = 0; m < 2; ++m)
            #pragma unroll
            for (int n = 0; n < 4; ++n)
                #pragma unroll
                for (int j = 0; j < 4; ++j)
                    red[(wave * 32 + m * 16 + r4 + j) * 68 + n * 16 + (lane & 15)] =
                        acc[m][n][j];
    }
    __syncthreads();
    if (wave >= 4) {
        #pragma unroll
        for (int m = 0; m < 2; ++m)
            #pragma unroll
            for (int n = 0; n < 4; ++n)
                #pragma unroll
                for (int j = 0; j < 4; ++j)
                    red[((wave - 4) * 32 + m * 16 + r4 + j) * 68 + n * 16 + (lane & 15)] +=
                        acc[m][n][j];
    }
    __syncthreads();
    for (int e = tid; e < 32 * 64; e += 512) {
        const int r = e >> 6, cc = e & 63;
        float s = red[(0 * 32 + r) * 68 + cc] + red[(1 * 32 + r) * 68 + cc]
                + red[(2 * 32 + r) * 68 + cc] + red[(3 * 32 + r) * 68 + cc];
        h_lds[r * 80 + cc] = f2bf1(s);
    }
    __syncthreads();

    // ---- phase 3: out[32][4096] = h @ b^T; wave w -> cols [w*512, +512) ----
    bf16x8 hf[4];
    #pragma unroll
    for (int ks = 0; ks < 4; ++ks)
        hf[ks] = *(const bf16x8*)(h_lds + (lane & 31) * 80 + ks * 16 + ((lane >> 5) << 3));

    #pragma unroll
    for (int n = 0; n < 16; ++n) {
        const int cb32 = wave * 16 + n;
        const int col  = cb32 * 32 + (lane & 31);
        f32x16 a2;
        #pragma unroll
        for (int j = 0; j < 16; ++j) a2[j] = 0.f;
        #pragma unroll
        for (int ks = 0; ks < 4; ++ks) {
            bf16x8 bf = *(const bf16x8*)(bpk + ((size_t)((cb32 * 4 + ks) * 64 + lane) << 3));
            a2 = __builtin_amdgcn_mfma_f32_32x32x16_bf16(hf[ks], bf, a2, 0, 0, 0);
        }
        #pragma unroll
        for (int reg = 0; reg < 16; ++reg) {
            const int r = (reg & 3) + 8 * (reg >> 2) + ((lane >> 5) << 2);
            __builtin_nontemporal_store(a2[reg],
                &out[(size_t)(rb + r) * D_MODEL + col]);
        }
    }
}

// ---------------------------------------------------------------------------
extern "C" void kernel_launch(void* const* d_in, const int* in_sizes, int n_in,
                              void* d_out, int out_size, void* d_ws, size_t ws_size,
                              hipStream_t stream) {
    (void)n_in; (void)out_size; (void)ws_size;
    const float* x   = (const float*)d_in[0];
    const int*   qa  = (const int*)d_in[1];
    const float* qas = (const float*)d_in[2];
    const int*   qb  = (const int*)d_in[3];
    const float* qbs = (const float*)d_in[4];
    float* out = (float*)d_out;

    const int T = in_sizes[0] / D_MODEL;   // 16384

    short* apk = (short*)d_ws;                       // 64*4096 bf16 packed
    short* bpk = apk + (size_t)RANK * D_MODEL;       // 4096*64 bf16 packed

    dequant_pack_kernel<<<128, 256, 0, stream>>>(qa, qas, qb, qbs, apk, bpk);
    fused_kernel<<<T / M_BLK, 512, 0, stream>>>(x, apk, bpk, out);
}